// Round 6
// baseline (5144.938 us; speedup 1.0000x reference)
//
#include <hip/hip_runtime.h>
#include <cstdint>

// ---------- types / helpers ----------
typedef __attribute__((ext_vector_type(8))) short short8;   // 8 x bf16 (4 VGPRs)
typedef __attribute__((ext_vector_type(4))) float f32x4;
typedef __attribute__((ext_vector_type(4))) int i32x4;
typedef unsigned short us16;
typedef unsigned char u8;

#define DEV __device__ __forceinline__

DEV us16 f2bf(float f){
  union { float f; unsigned u; } v; v.f = f;
  unsigned r = (v.u + 0x7FFFu + ((v.u >> 16) & 1u)) >> 16;   // RNE
  return (us16)r;
}
DEV u8 f2fp8(float f){      // OCP e4m3fn via HW cvt (RNE, saturating)
  int p = __builtin_amdgcn_cvt_pk_fp8_f32(f, f, 0, false);
  return (u8)(p & 0xFF);
}
template<int SEL> DEV float fp8tof(int dw){
#if __has_builtin(__builtin_amdgcn_cvt_f32_fp8)
  return __builtin_amdgcn_cvt_f32_fp8(dw, SEL);
#else
  int b = (dw >> (8*SEL)) & 255;
  int e = (b>>3)&15, m = b&7;
  float v;
  if (e){ union{unsigned u; float f;} x; x.u = (unsigned)(((e+120)<<23) | (m<<20)); v = x.f; }
  else v = (float)m * 0.001953125f;
  return (b & 128) ? -v : v;
#endif
}
DEV float fsig(float x){
  float e = __builtin_amdgcn_exp2f(-1.4426950408889634f * x);
  return __builtin_amdgcn_rcpf(1.0f + e);
}
DEV float ftanh(float x){
  float e = __builtin_amdgcn_exp2f(-2.8853900817779268f * x);
  return fmaf(2.0f, __builtin_amdgcn_rcpf(1.0f + e), -1.0f);
}
DEV float fsoftplus(float x){
  float ax = fabsf(x);
  float e = __builtin_amdgcn_exp2f(-1.4426950408889634f * ax);
  float l = 0.69314718055994531f * __builtin_amdgcn_logf(1.0f + e);
  return fmaxf(x, 0.0f) + l;
}
DEV f32x4 mfma16(short8 a, short8 b, f32x4 c){
  return __builtin_amdgcn_mfma_f32_16x16x32_bf16(a, b, c, 0, 0, 0);
}
DEV f32x4 mfma16f8(long a, long b, f32x4 c){
  return __builtin_amdgcn_mfma_f32_16x16x32_fp8_fp8(a, b, c, 0, 0, 0);
}

// Dims: B=256, T=WN=200, HH=256/dir, gates=1024, tags K=12.
// MFMA 16x16x32 fragment layouts (dtype-independent, HW-verified):
//   A: lane L holds A[m=L&15][k=(L>>4)*8+j]
//   B: lane L holds B[k=(L>>4)*8+j][n=L&15]
//   D: lane L reg r holds D[row=(L>>4)*4+r][col=L&15]

// ---------- preprocessing ----------

__global__ void k_embed(const int* __restrict__ chars, const float* __restrict__ emb,
                        u8* __restrict__ out){
  int tid = blockIdx.x * 256 + threadIdx.x;          // 256*200*32
  if (tid >= 256*200*32) return;
  int c = tid & 31, bt = tid >> 5;
  int idx = chars[bt];
  float v = (c < 30) ? emb[idx * 30 + c] : 0.0f;
  out[tid] = f2fp8(v);
}

__global__ void k_cvt8(const float* __restrict__ src, u8* __restrict__ dst, int n){
  int tid = blockIdx.x * 256 + threadIdx.x;
  if (tid < n) dst[tid] = f2fp8(src[tid]);
}

__global__ void k_zf(int* __restrict__ flags){ flags[threadIdx.x] = 0; }

// LSTM weights [Whh|Wih] -> fp8, per-half j-permuted so k_lstm uses static reg idx.
// layout chunk = ((H*8+w)*4+gt)*KC + j ; j<4: own kcs (H*4+j), j<8: partner kcs,
// j==8 (char): x chunk. gate row g = gt*256 + H*128 + w*16 + lrow.
__global__ void k_swz_lstm(const float* __restrict__ Whh, const float* __restrict__ Wih,
                           int I, int KC, u8* __restrict__ dst){
  int tid = blockIdx.x * 256 + threadIdx.x;
  int total = 64 * KC * 512;
  if (tid >= total) return;
  int e = tid & 511, chunk = tid >> 9;
  int L = e >> 3, jj = e & 7;
  int j = chunk % KC; int rem = chunk / KC;
  int gt = rem & 3, w = (rem >> 2) & 7, H = rem >> 5;
  int kc = (j < 4) ? (H * 4 + j) : (j < 8 ? (1 - H) * 4 + (j - 4) : 8);
  int g = gt * 256 + H * 128 + w * 16 + (L & 15);
  int k = kc * 32 + (L >> 4) * 8 + jj;
  float v = 0.0f;
  if (k < 256) v = Whh[g * 256 + k];
  else if (k - 256 < I) v = Wih[g * I + (k - 256)];
  dst[tid] = f2fp8(v);
}

// Wih (word, [1024 x 128]) B-fragment swizzle: [ntile(64)][kc(4)][lane x 8B]
__global__ void k_swz_gin(const float* __restrict__ Wih, u8* __restrict__ dst){
  int tid = blockIdx.x * 256 + threadIdx.x;          // 64*4*512
  if (tid >= 64*4*512) return;
  int e = tid & 511, chunk = tid >> 9;
  int L = e >> 3, j = e & 7;
  int kc = chunk & 3, ntile = chunk >> 2;
  int g = ntile * 16 + (L & 15);
  int k = kc * 32 + (L >> 4) * 8 + j;
  dst[tid] = f2fp8(Wih[g * 128 + k]);
}

// FF weight swizzle (bf16): [ntile][kc][lane x 8], zero-padded past N/K
__global__ void k_swz_ff(const float* __restrict__ W, int N, int Kd, int KC,
                         us16* __restrict__ dst, int total){
  int tid = blockIdx.x * 256 + threadIdx.x;
  if (tid >= total) return;
  int e = tid & 511, chunk = tid >> 9;
  int L = e >> 3, j = e & 7;
  int kc = chunk % KC; int nt = chunk / KC;
  int g = nt * 16 + (L & 15);
  int k = kc * 32 + (L >> 4) * 8 + j;
  float v = (g < N && k < Kd) ? W[g * Kd + k] : 0.0f;
  dst[tid] = f2bf(v);
}

__global__ void k_zpad(us16* __restrict__ xcat){
  int tid = blockIdx.x * 256 + threadIdx.x;          // 51200*24
  if (tid >= 51200 * 24) return;
  int r = tid / 24, c = tid - r * 24;
  xcat[r * 736 + 712 + c] = 0;
}

// ---------- gin precompute: gin = fp8(x @ Wih^T + b), split-block consumer layout ----------
// grid = 2*16*50 x 512 thr; each block does 4 timesteps with weights held in regs.
// out: gin[(((d*16+slice)*200 + t)*2 + half)*8192 + ctid*16 + (gt*4 + r)]
__global__ __launch_bounds__(512) void k_gin(
    const u8* __restrict__ words_f8, const u8* __restrict__ wswg_f,
    const u8* __restrict__ wswg_b, const float* __restrict__ bias_f,
    const float* __restrict__ bias_b, u8* __restrict__ gin)
{
  const int blk = blockIdx.x;
  const int d = blk / 800, rem = blk - d * 800;
  const int slice = rem / 50, tq = rem - slice * 50;
  const u8* Wsw = d ? wswg_b : wswg_f;
  const float* bias = d ? bias_b : bias_f;
  __shared__ u8 xs[16 * 136];
  __shared__ u8 sbuf[2 * 512 * 16];
  const int tid = threadIdx.x;
  const int wv = tid >> 6, L = tid & 63;
  const int lrow = L & 15, lq = L >> 4;
  const long* WswV = (const long*)Wsw;

  long wr[8][4];
  #pragma unroll
  for (int nt = 0; nt < 8; ++nt)
    #pragma unroll
    for (int kc = 0; kc < 4; ++kc)
      wr[nt][kc] = WswV[((wv * 8 + nt) * 4 + kc) * 64 + L];
  float bv[8];
  #pragma unroll
  for (int nt = 0; nt < 8; ++nt) bv[nt] = bias[wv * 128 + nt * 16 + lrow];

  for (int i = 0; i < 4; ++i){
    const int t = tq * 4 + i;
    if (tid < 256){
      int r = tid >> 4, c8 = (tid & 15) * 8;
      *(long*)&xs[r * 136 + c8] =
        *(const long*)&words_f8[((long)(slice * 16 + r) * 200 + t) * 128 + c8];
    }
    __syncthreads();
    f32x4 acc[8];
    #pragma unroll
    for (int nt = 0; nt < 8; ++nt) acc[nt] = (f32x4){bv[nt], bv[nt], bv[nt], bv[nt]};
    #pragma unroll
    for (int kc = 0; kc < 4; ++kc){
      long af = *(const long*)&xs[lrow * 136 + kc * 32 + lq * 8];
      #pragma unroll
      for (int nt = 0; nt < 8; ++nt)
        acc[nt] = mfma16f8(af, wr[nt][kc], acc[nt]);
    }
    #pragma unroll
    for (int nt = 0; nt < 8; ++nt){
      int gcol = wv * 128 + nt * 16 + lrow;
      int gt = gcol >> 8, hcol = gcol & 255;
      int half = hcol >> 7, c = hcol & 127;
      int ctid = (c >> 4) * 64 + lq * 16 + (c & 15);
      #pragma unroll
      for (int r = 0; r < 4; ++r)
        sbuf[half * 8192 + ctid * 16 + gt * 4 + r] = f2fp8(acc[nt][r]);
    }
    __syncthreads();
    long ob = (((long)(d * 16 + slice) * 200 + t) * 2) * 8192 + tid * 16;
    *(i32x4*)&gin[ob]        = *(const i32x4*)&sbuf[tid * 16];
    *(i32x4*)&gin[ob + 8192] = *(const i32x4*)&sbuf[8192 + tid * 16];
    __syncthreads();
  }
}

// ---------- bidirectional LSTM, gate-col split across paired blocks ----------
// grid = 128 x 512 thr. g: dir=g>>5, half=(g>>4)&1, slice=g&15; partner = g^16
// (same XCD under RR mapping). Block computes h-cols [half*128, half*128+128).
// Per step: own-half h from LDS, partner half from exbuf (L2) after flag spin.
// Weights fully register-resident (j-permuted, static indices).
template<int KC, int SA, bool GIN>
DEV void lstm_body(u8* abuf, const u8* __restrict__ xbuf, const u8* __restrict__ gin,
                   const u8* __restrict__ Wsw, const float* __restrict__ bias,
                   const int* __restrict__ lens, us16* __restrict__ hout,
                   u8* __restrict__ exbuf, volatile int* flags,
                   int g, int half, int b0, int hcol0, bool rev, long ginSlice)
{
  constexpr int BUF = 16 * SA;
  const int tid = threadIdx.x;
  const int w = tid >> 6, L = tid & 63;
  const int lrow = L & 15, lq = L >> 4;
  const int partner = g ^ 16;
  u8* exmy = exbuf + (long)g * 4096;
  const u8* expr = exbuf + (long)partner * 4096;
  const long* WswV = (const long*)Wsw;

  long wr[4][KC];
  #pragma unroll
  for (int gt = 0; gt < 4; ++gt)
    #pragma unroll
    for (int j = 0; j < KC; ++j)
      wr[gt][j] = WswV[(((half * 8 + w) * 4 + gt) * KC + j) * 64 + L];

  float bv[4];
  if constexpr (!GIN){
    #pragma unroll
    for (int gt = 0; gt < 4; ++gt)
      bv[gt] = bias[gt * 256 + half * 128 + w * 16 + lrow];
  }

  unsigned lpack = 0;
  #pragma unroll
  for (int r = 0; r < 4; ++r)
    lpack |= (unsigned)lens[b0 + lq * 4 + r] << (8 * r);

  float cst[4];
  u8 hreg[4];
  #pragma unroll
  for (int r = 0; r < 4; ++r){ cst[r] = 0.0f; hreg[r] = 0; }

  // zero own-h region of buf0; char: stage x(t0)
  if (tid < 256){
    int r = tid >> 4, c8 = (tid & 15) * 8;
    *(long*)&abuf[r * SA + c8] = 0;
  }
  const int t0 = rev ? 199 : 0;
  if constexpr (!GIN){
    if (tid < 64){
      int r = tid >> 2, c8 = (tid & 3) * 8;
      *(long*)&abuf[r * SA + 128 + c8] =
        *(const long*)&xbuf[((long)(b0 + r) * 200 + t0) * 32 + c8];
    }
  }
  i32x4 gA{};
  if constexpr (GIN)
    gA = *(const i32x4*)&gin[(((ginSlice) * 200 + t0) * 2 + half) * 8192 + tid * 16];
  __syncthreads();

  for (int tau = 0; tau < 200; ++tau){
    const int t = rev ? (199 - tau) : tau;
    u8* cur = abuf + (tau & 1) * BUF;
    u8* nxt = abuf + ((tau & 1) ^ 1) * BUF;

    // A fragments: own half from LDS, partner half from exbuf (0 at tau==0)
    long afO[4], afP[4], afX = 0;
    #pragma unroll
    for (int i = 0; i < 4; ++i)
      afO[i] = *(const long*)&cur[lrow * SA + i * 32 + lq * 8];
    if constexpr (KC == 9)
      afX = *(const long*)&cur[lrow * SA + 128 + lq * 8];
    if (tau == 0){
      #pragma unroll
      for (int i = 0; i < 4; ++i) afP[i] = 0;
    } else {
      const u8* pex = expr + ((tau - 1) & 1) * 2048 + lrow * 128 + lq * 8;
      #pragma unroll
      for (int i = 0; i < 4; ++i) afP[i] = *(const long*)(pex + i * 32);
    }

    f32x4 acc[4];
    if constexpr (GIN){
      int g4[4];
      *(i32x4*)g4 = gA;
      #pragma unroll
      for (int gt = 0; gt < 4; ++gt)
        acc[gt] = (f32x4){fp8tof<0>(g4[gt]), fp8tof<1>(g4[gt]),
                          fp8tof<2>(g4[gt]), fp8tof<3>(g4[gt])};
      int tn = (tau < 199) ? (rev ? 198 - tau : tau + 1) : t;
      gA = *(const i32x4*)&gin[(((ginSlice) * 200 + tn) * 2 + half) * 8192 + tid * 16];
    } else {
      #pragma unroll
      for (int gt = 0; gt < 4; ++gt)
        acc[gt] = (f32x4){bv[gt], bv[gt], bv[gt], bv[gt]};
    }

    // own-half (+x) MFMAs first: cover partner-load latency
    #pragma unroll
    for (int i = 0; i < 4; ++i)
      #pragma unroll
      for (int gt = 0; gt < 4; ++gt)
        acc[gt] = mfma16f8(afO[i], wr[gt][i], acc[gt]);
    if constexpr (KC == 9){
      #pragma unroll
      for (int gt = 0; gt < 4; ++gt)
        acc[gt] = mfma16f8(afX, wr[gt][8], acc[gt]);
    }
    #pragma unroll
    for (int i = 0; i < 4; ++i)
      #pragma unroll
      for (int gt = 0; gt < 4; ++gt)
        acc[gt] = mfma16f8(afP[i], wr[gt][4 + i], acc[gt]);

    // cell epilogue (4 cells/thread), write own half to nxt LDS + hout
    #pragma unroll
    for (int r = 0; r < 4; ++r){
      const int bm = lq * 4 + r;
      const bool mk = t < (int)((lpack >> (8 * r)) & 255u);
      const long gbase = ((long)(b0 + bm) * 200 + t) * 512 + hcol0 + half * 128 + w * 16 + lrow;
      float gi = acc[0][r], gf = acc[1][r], gg = acc[2][r], go = acc[3][r];
      float cn = fsig(gf) * cst[r] + fsig(gi) * ftanh(gg);
      float hn = fsig(go) * ftanh(cn);
      u8 hb;
      if (mk){
        cst[r] = cn;
        hb = f2fp8(hn);
        hreg[r] = hb;
        hout[gbase] = f2bf(hn);
      } else {
        hb = hreg[r];
        hout[gbase] = 0;
      }
      nxt[bm * SA + w * 16 + lrow] = hb;
    }

    if constexpr (!GIN){
      if (tau < 199){
        int tn = rev ? (198 - tau) : (tau + 1);
        if (tid < 64){
          int r = tid >> 2, c8 = (tid & 3) * 8;
          *(long*)&nxt[r * SA + 128 + c8] =
            *(const long*)&xbuf[((long)(b0 + r) * 200 + tn) * 32 + c8];
        }
      }
    }

    if (tau < 199){
      __syncthreads();                       // nxt own-h complete
      if (tid < 128){                        // waves 0,1: flush 2KB to exbuf
        const u8* s = nxt + (tid >> 3) * SA + (tid & 7) * 16;
        long v0 = *(const long*)s, v1 = *(const long*)(s + 8);
        long* dgl = (long*)(exmy + (tau & 1) * 2048 + (tid >> 3) * 128 + (tid & 7) * 16);
        dgl[0] = v0; dgl[1] = v1;
        __threadfence();                     // drain waves 0,1 stores
      }
      __syncthreads();
      if (tid == 0)
        __hip_atomic_store((int*)&flags[g], tau + 1, __ATOMIC_RELEASE, __HIP_MEMORY_SCOPE_AGENT);
      while (__hip_atomic_load((int*)&flags[partner], __ATOMIC_ACQUIRE, __HIP_MEMORY_SCOPE_AGENT) < tau + 1)
        __builtin_amdgcn_s_sleep(2);
    }
  }
}

__global__ __launch_bounds__(512, 2) void k_lstm(
    const u8* __restrict__ char_vec, const u8* __restrict__ gin,
    const u8* __restrict__ wsw_cf, const u8* __restrict__ wsw_cb,
    const u8* __restrict__ wsw_wf, const u8* __restrict__ wsw_wb,
    const float* __restrict__ b_cf, const float* __restrict__ b_cb,
    const int* __restrict__ len_char, const int* __restrict__ len_word,
    us16* __restrict__ h_char, us16* __restrict__ h_word,
    u8* __restrict__ exbuf, int* __restrict__ flags)
{
  const int g = blockIdx.x;
  const int dir = g >> 5, half = (g >> 4) & 1, slice = g & 15;
  const int b0 = slice * 16;
  __shared__ __align__(16) u8 abuf[2 * 16 * 176];

  if (dir == 0)
    lstm_body<9, 176, false>(abuf, char_vec, nullptr, wsw_cf, b_cf, len_char,
                             h_char, exbuf, flags, g, half, b0, 0, false, 0);
  else if (dir == 1)
    lstm_body<9, 176, false>(abuf, char_vec, nullptr, wsw_cb, b_cb, len_char,
                             h_char, exbuf, flags, g, half, b0, 256, true, 0);
  else if (dir == 2)
    lstm_body<8, 144, true>(abuf, nullptr, gin, wsw_wf, nullptr, len_word,
                            h_word, exbuf, flags, g, half, b0, 0, false, slice);
  else
    lstm_body<8, 144, true>(abuf, nullptr, gin, wsw_wb, nullptr, len_word,
                            h_word, exbuf, flags, g, half, b0, 256, true, 16 + slice);
}

// ---------- generic FF GEMM: out = softplus(A[M,K]bf16 @ Wsw^T + bias) ----------
__global__ __launch_bounds__(256) void k_gemm(
    const us16* __restrict__ A, int KC, const us16* __restrict__ Wsw,
    const float* __restrict__ bias, int N,
    void* __restrict__ outp, int ostride, int ocol0, int out_f32)
{
  const int tid = threadIdx.x;
  const int w = tid >> 6, L = tid & 63;
  const int lrow = L & 15, lq = L >> 4;
  const int m0base = blockIdx.x * 128;
  const int ntbase = blockIdx.y * 8;
  const int Kd = KC * 32;
  __shared__ us16 At[128 * 40];            // 20 dw stride -> <=2-way banks
  f32x4 acc[8][2] = {};
  const short8* WswV = (const short8*)Wsw;
  const int srow = tid >> 1, scol = (tid & 1) * 16;

  for (int kc = 0; kc < KC; ++kc){
    const long abase = (long)(m0base + srow) * Kd + kc * 32 + scol;
    short8 v0 = *(const short8*)&A[abase];
    short8 v1 = *(const short8*)&A[abase + 8];
    *(short8*)&At[srow * 40 + scol] = v0;
    *(short8*)&At[srow * 40 + scol + 8] = v1;
    __syncthreads();
    short8 af0 = *(const short8*)&At[(w * 32 + lrow) * 40 + lq * 8];
    short8 af1 = *(const short8*)&At[(w * 32 + 16 + lrow) * 40 + lq * 8];
    #pragma unroll
    for (int nt = 0; nt < 8; ++nt){
      short8 bf = WswV[((ntbase + nt) * KC + kc) * 64 + L];
      acc[nt][0] = mfma16(af0, bf, acc[nt][0]);
      acc[nt][1] = mfma16(af1, bf, acc[nt][1]);
    }
    __syncthreads();
  }
  #pragma unroll
  for (int nt = 0; nt < 8; ++nt){
    const int col = (ntbase + nt) * 16 + lrow;
    if (col >= N) continue;
    const float bvv = bias[col];
    #pragma unroll
    for (int m0 = 0; m0 < 2; ++m0){
      #pragma unroll
      for (int r = 0; r < 4; ++r){
        float v = fsoftplus(acc[nt][m0][r] + bvv);
        const int row = m0base + w * 32 + m0 * 16 + lq * 4 + r;
        if (out_f32) ((float*)outp)[(long)row * ostride + ocol0 + col] = v;
        else         ((us16*)outp)[(long)row * ostride + ocol0 + col] = f2bf(v);
      }
    }
  }
}

// ---------- CRF NLL: one wave per batch row ----------
__global__ void k_crf(const float* __restrict__ logits, const int* __restrict__ tags,
                      const int* __restrict__ lens, const float* __restrict__ trans,
                      float* __restrict__ nll)
{
  const int b = blockIdx.x;
  const int lane = threadIdx.x;            // 64
  __shared__ float alpha[12];
  __shared__ float tmp[12];
  float tcol[12];
  if (lane < 12){
    #pragma unroll
    for (int i = 0; i < 12; ++i) tcol[i] = trans[i * 12 + lane];
    alpha[lane] = 0.0f;
  }
  const int len = lens[b];
  __syncthreads();
  for (int t = 0; t < len; ++t){
    float an = 0.0f;
    if (lane < 12){
      float mx = -3.0e38f;
      #pragma unroll
      for (int i = 0; i < 12; ++i) mx = fmaxf(mx, alpha[i] + tcol[i]);
      float ss = 0.0f;
      #pragma unroll
      for (int i = 0; i < 12; ++i)
        ss += __builtin_amdgcn_exp2f(1.4426950408889634f * (alpha[i] + tcol[i] - mx));
      an = logits[((long)b * 200 + t) * 12 + lane] + mx
         + 0.69314718055994531f * __builtin_amdgcn_logf(ss);
    }
    __syncthreads();
    if (lane < 12) alpha[lane] = an;
    __syncthreads();
  }
  if (lane < 12) tmp[lane] = alpha[lane] + trans[lane * 12 + 11];   // + trans[:,STOP]
  __syncthreads();
  float rs = 0.0f;
  for (int t = lane; t < len; t += 64){
    int tg = tags[b * 200 + t];
    int pv = (t == 0) ? 10 : tags[b * 200 + t - 1];                 // START=10
    rs += logits[((long)b * 200 + t) * 12 + tg] + trans[pv * 12 + tg];
  }
  #pragma unroll
  for (int off = 32; off > 0; off >>= 1) rs += __shfl_down(rs, off, 64);
  if (lane == 0){
    float mx = -3.0e38f;
    for (int i = 0; i < 12; ++i) mx = fmaxf(mx, tmp[i]);
    float ss = 0.0f;
    for (int i = 0; i < 12; ++i)
      ss += __builtin_amdgcn_exp2f(1.4426950408889634f * (tmp[i] - mx));
    float total = mx + 0.69314718055994531f * __builtin_amdgcn_logf(ss);
    rs += trans[tags[b * 200 + len - 1] * 12 + 11];                 // trans[last, STOP]
    nll[b] = total - rs;
  }
}

__global__ void k_sum(const float* __restrict__ nll, float* __restrict__ out){
  __shared__ float red[256];
  int t = threadIdx.x;
  red[t] = nll[t];
  __syncthreads();
  for (int s = 128; s > 0; s >>= 1){
    if (t < s) red[t] += red[t + s];
    __syncthreads();
  }
  if (t == 0) out[0] = red[0];
}

// ---------- launcher ----------
extern "C" void kernel_launch(void* const* d_in, const int* in_sizes, int n_in,
                              void* d_out, int out_size, void* d_ws, size_t ws_size,
                              hipStream_t stream)
{
  (void)in_sizes; (void)n_in; (void)out_size; (void)ws_size;
  const int*   characters = (const int*)  d_in[0];
  const float* words      = (const float*)d_in[1];
  const int*   tags       = (const int*)  d_in[2];
  const int*   len_char   = (const int*)  d_in[3];
  const int*   len_word   = (const int*)  d_in[4];
  const float* char_emb   = (const float*)d_in[5];
  const float* char_Wih_f = (const float*)d_in[6];
  const float* char_Whh_f = (const float*)d_in[7];
  const float* char_b_f   = (const float*)d_in[8];
  const float* char_Wih_b = (const float*)d_in[9];
  const float* char_Whh_b = (const float*)d_in[10];
  const float* char_b_b   = (const float*)d_in[11];
  const float* char_lin_W = (const float*)d_in[12];
  const float* char_lin_b = (const float*)d_in[13];
  const float* word_Wih_f = (const float*)d_in[14];
  const float* word_Whh_f = (const float*)d_in[15];
  const float* word_b_f   = (const float*)d_in[16];
  const float* word_Wih_b = (const float*)d_in[17];
  const float* word_Whh_b = (const float*)d_in[18];
  const float* word_b_b   = (const float*)d_in[19];
  const float* word_lin_W = (const float*)d_in[20];
  const float* word_lin_b = (const float*)d_in[21];
  const float* lin1_W     = (const float*)d_in[22];
  const float* lin1_b     = (const float*)d_in[23];
  const float* lin2_W     = (const float*)d_in[24];
  const float* lin2_b     = (const float*)d_in[25];
  const float* tag_W      = (const float*)d_in[26];
  const float* tag_b      = (const float*)d_in[27];
  const float* trans      = (const float*)d_in[28];

  char* ws = (char*)d_ws;
  size_t off = 0;
  auto take = [&](size_t bytes) -> char* {
    char* p = ws + off;
    off = (off + bytes + 511) & ~(size_t)511;
    return p;
  };
  u8*   char_vec = (u8*)take((size_t)256*200*32);          //  1.6 MB fp8
  u8*   words_f8 = (u8*)take((size_t)256*200*128);         //  6.3 MB fp8
  u8*   wsw_cf   = (u8*)take((size_t)64*9*512);
  u8*   wsw_cb   = (u8*)take((size_t)64*9*512);
  u8*   wsw_wf   = (u8*)take((size_t)64*8*512);
  u8*   wsw_wb   = (u8*)take((size_t)64*8*512);
  u8*   wswgin_f = (u8*)take((size_t)64*4*512);
  u8*   wswgin_b = (u8*)take((size_t)64*4*512);
  us16* wswg1    = (us16*)take((size_t)32*16*512*2);
  us16* wswg2    = (us16*)take((size_t)16*16*512*2);
  us16* wswg3    = (us16*)take((size_t)32*23*512*2);
  us16* wswg4    = (us16*)take((size_t)16*16*512*2);
  us16* wswg5    = (us16*)take((size_t)8*8*512*2);
  float* logits  = (float*)take((size_t)51200*12*4);
  float* nll     = (float*)take((size_t)256*4);
  u8*   exbuf    = (u8*)take((size_t)128*2*2048);          // 512 KB h-exchange
  int*  flags    = (int*)take((size_t)128*4);
  us16* h_char   = (us16*)take((size_t)51200*512*2);       // 50 MB
  us16* h_word   = (us16*)take((size_t)51200*512*2);       // 50 MB
  u8*   gin      = (u8*)take((size_t)2*16*200*2*8192);     // 100 MB; dead after k_lstm
  us16* x_cat    = (us16*)gin;   // 72 MB, written after k_lstm -> safe alias
  us16* x1 = h_char;   // dead after G1
  us16* x2 = h_word;   // dead after G2

  // preprocessing
  k_zf<<<1, 128, 0, stream>>>(flags);
  k_embed<<<6400, 256, 0, stream>>>(characters, char_emb, char_vec);
  k_cvt8<<<(256*200*128 + 255)/256, 256, 0, stream>>>(words, words_f8, 256*200*128);
  k_swz_lstm<<<(64*9*512 + 255)/256, 256, 0, stream>>>(char_Whh_f, char_Wih_f, 30, 9, wsw_cf);
  k_swz_lstm<<<(64*9*512 + 255)/256, 256, 0, stream>>>(char_Whh_b, char_Wih_b, 30, 9, wsw_cb);
  k_swz_lstm<<<(64*8*512 + 255)/256, 256, 0, stream>>>(word_Whh_f, word_Wih_f, 0, 8, wsw_wf);
  k_swz_lstm<<<(64*8*512 + 255)/256, 256, 0, stream>>>(word_Whh_b, word_Wih_b, 0, 8, wsw_wb);
  k_swz_gin<<<(64*4*512 + 255)/256, 256, 0, stream>>>(word_Wih_f, wswgin_f);
  k_swz_gin<<<(64*4*512 + 255)/256, 256, 0, stream>>>(word_Wih_b, wswgin_b);
  k_swz_ff<<<(32*16*512 + 255)/256, 256, 0, stream>>>(char_lin_W, 512, 512, 16, wswg1, 32*16*512);
  k_swz_ff<<<(16*16*512 + 255)/256, 256, 0, stream>>>(word_lin_W, 200, 512, 16, wswg2, 16*16*512);
  k_swz_ff<<<(32*23*512 + 255)/256, 256, 0, stream>>>(lin1_W, 512, 712, 23, wswg3, 32*23*512);
  k_swz_ff<<<(16*16*512 + 255)/256, 256, 0, stream>>>(lin2_W, 256, 512, 16, wswg4, 16*16*512);
  k_swz_ff<<<(8*8*512 + 255)/256, 256, 0, stream>>>(tag_W, 12, 256, 8, wswg5, 8*8*512);

  // gin precompute (word Wih.x + b, fp8, split-block lane layout, 4t/block)
  k_gin<<<1600, 512, 0, stream>>>(words_f8, wswgin_f, wswgin_b, word_b_f, word_b_b, gin);

  // recurrences: 128 blocks (gate-col split, paired h-exchange)
  k_lstm<<<128, 512, 0, stream>>>(char_vec, gin, wsw_cf, wsw_cb, wsw_wf, wsw_wb,
                                  char_b_f, char_b_b, len_char, len_word,
                                  h_char, h_word, exbuf, flags);

  // x_cat padding (x_cat aliases gin -> must run after k_lstm)
  k_zpad<<<4800, 256, 0, stream>>>(x_cat);

  // feed-forward chain (bf16)
  k_gemm<<<dim3(400, 4), 256, 0, stream>>>(h_char, 16, wswg1, char_lin_b, 512, x_cat, 736,   0, 0);
  k_gemm<<<dim3(400, 2), 256, 0, stream>>>(h_word, 16, wswg2, word_lin_b, 200, x_cat, 736, 512, 0);
  k_gemm<<<dim3(400, 4), 256, 0, stream>>>(x_cat, 23, wswg3, lin1_b, 512, x1, 512, 0, 0);
  k_gemm<<<dim3(400, 2), 256, 0, stream>>>(x1,    16, wswg4, lin2_b, 256, x2, 256, 0, 0);
  k_gemm<<<dim3(400, 1), 256, 0, stream>>>(x2,     8, wswg5, tag_b,   12, logits, 12, 0, 1);

  // CRF
  k_crf<<<256, 64, 0, stream>>>(logits, tags, len_char, trans, nll);
  k_sum<<<1, 256, 0, stream>>>(nll, (float*)d_out);
}

// Round 7
// 959.055 us; speedup vs baseline: 5.3646x; 5.3646x over previous
//
#include <hip/hip_runtime.h>
#include <cstdint>

// ---------- types / helpers ----------
typedef __attribute__((ext_vector_type(8))) short short8;   // 8 x bf16 (4 VGPRs)
typedef __attribute__((ext_vector_type(4))) float f32x4;
typedef __attribute__((ext_vector_type(4))) int i32x4;
typedef unsigned short us16;
typedef unsigned char u8;

#define DEV __device__ __forceinline__

DEV us16 f2bf(float f){
  union { float f; unsigned u; } v; v.f = f;
  unsigned r = (v.u + 0x7FFFu + ((v.u >> 16) & 1u)) >> 16;   // RNE
  return (us16)r;
}
DEV u8 f2fp8(float f){      // OCP e4m3fn via HW cvt (RNE, saturating)
  int p = __builtin_amdgcn_cvt_pk_fp8_f32(f, f, 0, false);
  return (u8)(p & 0xFF);
}
template<int SEL> DEV float fp8tof(int dw){
#if __has_builtin(__builtin_amdgcn_cvt_f32_fp8)
  return __builtin_amdgcn_cvt_f32_fp8(dw, SEL);
#else
  int b = (dw >> (8*SEL)) & 255;
  int e = (b>>3)&15, m = b&7;
  float v;
  if (e){ union{unsigned u; float f;} x; x.u = (unsigned)(((e+120)<<23) | (m<<20)); v = x.f; }
  else v = (float)m * 0.001953125f;
  return (b & 128) ? -v : v;
#endif
}
DEV float fsig(float x){
  float e = __builtin_amdgcn_exp2f(-1.4426950408889634f * x);
  return __builtin_amdgcn_rcpf(1.0f + e);
}
DEV float ftanh(float x){
  float e = __builtin_amdgcn_exp2f(-2.8853900817779268f * x);
  return fmaf(2.0f, __builtin_amdgcn_rcpf(1.0f + e), -1.0f);
}
DEV float fsoftplus(float x){
  float ax = fabsf(x);
  float e = __builtin_amdgcn_exp2f(-1.4426950408889634f * ax);
  float l = 0.69314718055994531f * __builtin_amdgcn_logf(1.0f + e);
  return fmaxf(x, 0.0f) + l;
}
DEV f32x4 mfma16(short8 a, short8 b, f32x4 c){
  return __builtin_amdgcn_mfma_f32_16x16x32_bf16(a, b, c, 0, 0, 0);
}
DEV f32x4 mfma16f8(long a, long b, f32x4 c){
  return __builtin_amdgcn_mfma_f32_16x16x32_fp8_fp8(a, b, c, 0, 0, 0);
}

// Dims: B=256, T=WN=200, HH=256/dir, gates=1024, tags K=12.
// MFMA 16x16x32 fragments: A: lane L holds A[m=L&15][k=(L>>4)*8+j];
// B: lane L holds B[k=(L>>4)*8+j][n=L&15]; D: lane L reg r = D[(L>>4)*4+r][L&15].
//
// h k-order permutation pi (so nt-pairs pack into one us16):
//   orig col c = w*32 + nt*16 + l  ->  stored p = w*32 + l*2 + nt
//   inverse: s -> k = (s>>5)*32 + (s&1)*16 + ((s&31)>>1)

// ---------- preprocessing ----------

__global__ void k_embed(const int* __restrict__ chars, const float* __restrict__ emb,
                        u8* __restrict__ out){
  int tid = blockIdx.x * 256 + threadIdx.x;          // 256*200*32
  if (tid >= 256*200*32) return;
  int c = tid & 31, bt = tid >> 5;
  int idx = chars[bt];
  float v = (c < 30) ? emb[idx * 30 + c] : 0.0f;
  out[tid] = f2fp8(v);
}

__global__ void k_cvt8(const float* __restrict__ src, u8* __restrict__ dst, int n){
  int tid = blockIdx.x * 256 + threadIdx.x;
  if (tid < n) dst[tid] = f2fp8(src[tid]);
}

// LSTM weights [Whh|Wih] -> fp8, R5 chunk order + pi-permuted h k-order.
// chunk = ((w*4+gt)*2+nt)*KC + kc; gate row g = gt*256 + w*32 + nt*16 + lrow.
__global__ void k_swz_lstm(const float* __restrict__ Whh, const float* __restrict__ Wih,
                           int I, int KC, u8* __restrict__ dst){
  int tid = blockIdx.x * 256 + threadIdx.x;
  int total = 64 * KC * 512;
  if (tid >= total) return;
  int e = tid & 511, chunk = tid >> 9;
  int L = e >> 3, j = e & 7;
  int kc = chunk % KC; int rem = chunk / KC;
  int nt = rem & 1, gt = (rem >> 1) & 3, w = rem >> 3;
  int g = gt * 256 + w * 32 + nt * 16 + (L & 15);
  int s = kc * 32 + (L >> 4) * 8 + j;                // stored k index
  float v = 0.0f;
  if (s < 256){
    int k = (s >> 5) * 32 + (s & 1) * 16 + ((s & 31) >> 1);
    v = Whh[g * 256 + k];
  } else {
    int xi = s - 256;
    if (xi < I) v = Wih[g * I + xi];
  }
  dst[tid] = f2fp8(v);
}

// Wih (word, [1024 x 128]) B-fragment swizzle: [ntile(64)][kc(4)][lane x 8B]
__global__ void k_swz_gin(const float* __restrict__ Wih, u8* __restrict__ dst){
  int tid = blockIdx.x * 256 + threadIdx.x;          // 64*4*512
  if (tid >= 64*4*512) return;
  int e = tid & 511, chunk = tid >> 9;
  int L = e >> 3, j = e & 7;
  int kc = chunk & 3, ntile = chunk >> 2;
  int g = ntile * 16 + (L & 15);
  int k = kc * 32 + (L >> 4) * 8 + j;
  dst[tid] = f2fp8(Wih[g * 128 + k]);
}

// FF fp8 weight swizzle for G1/G2 (Kd=512, KC=16), k pi-permuted per 256-half.
__global__ void k_swz_ff8(const float* __restrict__ W, int N, u8* __restrict__ dst, int total){
  int tid = blockIdx.x * 256 + threadIdx.x;
  if (tid >= total) return;
  int e = tid & 511, chunk = tid >> 9;
  int L = e >> 3, j = e & 7;
  int kc = chunk % 16; int nt = chunk / 16;
  int g = nt * 16 + (L & 15);
  int s = kc * 32 + (L >> 4) * 8 + j;                // 0..511 stored
  int base = (s >= 256) ? 256 : 0; int q = s - base;
  int k = base + (q >> 5) * 32 + (q & 1) * 16 + ((q & 31) >> 1);
  float v = (g < N) ? W[g * 512 + k] : 0.0f;
  dst[tid] = f2fp8(v);
}

// FF bf16 weight swizzle (G3/G4/G5): [ntile][kc][lane x 8], zero-padded
__global__ void k_swz_ff(const float* __restrict__ W, int N, int Kd, int KC,
                         us16* __restrict__ dst, int total){
  int tid = blockIdx.x * 256 + threadIdx.x;
  if (tid >= total) return;
  int e = tid & 511, chunk = tid >> 9;
  int L = e >> 3, j = e & 7;
  int kc = chunk % KC; int nt = chunk / KC;
  int g = nt * 16 + (L & 15);
  int k = kc * 32 + (L >> 4) * 8 + j;
  float v = (g < N && k < Kd) ? W[g * Kd + k] : 0.0f;
  dst[tid] = f2bf(v);
}

__global__ void k_zpad(us16* __restrict__ xcat){
  int tid = blockIdx.x * 256 + threadIdx.x;          // 51200*24
  if (tid >= 51200 * 24) return;
  int r = tid / 24, c = tid - r * 24;
  xcat[r * 736 + 712 + c] = 0;
}

// ---------- gin precompute: gin = fp8(x @ Wih^T + b), 4 timesteps/block ----------
// grid = 2*16*50 x 512 thr. Output (R5 consumer layout):
// gin[(((d*16+slice)*200+t)*512 + tid)*32 + gt*8 + nt*4 + r]
__global__ __launch_bounds__(512) void k_gin(
    const u8* __restrict__ words_f8, const u8* __restrict__ wswg_f,
    const u8* __restrict__ wswg_b, const float* __restrict__ bias_f,
    const float* __restrict__ bias_b, u8* __restrict__ gin)
{
  const int blk = blockIdx.x;
  const int d = blk / 800, rem = blk - d * 800;
  const int slice = rem / 50, tq = rem - slice * 50;
  const u8* Wsw = d ? wswg_b : wswg_f;
  const float* bias = d ? bias_b : bias_f;
  __shared__ u8 xs[16 * 136];
  __shared__ u8 sbuf[512 * 32];
  const int tid = threadIdx.x;
  const int wv = tid >> 6, L = tid & 63;
  const int lrow = L & 15, lq = L >> 4;
  const long* WswV = (const long*)Wsw;

  long wr[8][4];
  #pragma unroll
  for (int nt = 0; nt < 8; ++nt)
    #pragma unroll
    for (int kc = 0; kc < 4; ++kc)
      wr[nt][kc] = WswV[((wv * 8 + nt) * 4 + kc) * 64 + L];
  float bv[8];
  #pragma unroll
  for (int nt = 0; nt < 8; ++nt) bv[nt] = bias[wv * 128 + nt * 16 + lrow];

  for (int i = 0; i < 4; ++i){
    const int t = tq * 4 + i;
    if (tid < 256){
      int r = tid >> 4, c8 = (tid & 15) * 8;
      *(long*)&xs[r * 136 + c8] =
        *(const long*)&words_f8[((long)(slice * 16 + r) * 200 + t) * 128 + c8];
    }
    __syncthreads();
    f32x4 acc[8];
    #pragma unroll
    for (int nt = 0; nt < 8; ++nt) acc[nt] = (f32x4){bv[nt], bv[nt], bv[nt], bv[nt]};
    #pragma unroll
    for (int kc = 0; kc < 4; ++kc){
      long af = *(const long*)&xs[lrow * 136 + kc * 32 + lq * 8];
      #pragma unroll
      for (int nt = 0; nt < 8; ++nt)
        acc[nt] = mfma16f8(af, wr[nt][kc], acc[nt]);
    }
    #pragma unroll
    for (int nt = 0; nt < 8; ++nt){
      int gcol = wv * 128 + nt * 16 + lrow;
      int gt = gcol >> 8, w2 = (gcol >> 5) & 7, nt2 = (gcol >> 4) & 1;
      int tid2 = w2 * 64 + lq * 16 + lrow;
      #pragma unroll
      for (int r = 0; r < 4; ++r)
        sbuf[tid2 * 32 + gt * 8 + nt2 * 4 + r] = f2fp8(acc[nt][r]);
    }
    __syncthreads();
    long ob = (((long)(d * 16 + slice) * 200 + t) * 512 + tid) * 32;
    *(i32x4*)&gin[ob]      = *(const i32x4*)&sbuf[tid * 32];
    *(i32x4*)&gin[ob + 16] = *(const i32x4*)&sbuf[tid * 32 + 16];
    __syncthreads();
  }
}

// ---------- bidirectional LSTM (R5 structure + packed-fp8 epilogue) ----------
// grid = 64 x 512 thr (8 waves, 2/SIMD). dir = blockIdx>>4, slice = blockIdx&15.
// Wave w owns h-cols [w*32, w*32+32) x 4 gates; weights fully register-resident.
// h in LDS is pi-permuted fp8 (nt-pairs adjacent); hout is pi-permuted fp8 too.
// hout stores issued AFTER the barrier (retire under next step's MFMAs).
template<int KC, int XDIM, int SA, bool GIN>
DEV void lstm_body(u8* abuf, const u8* __restrict__ xbuf, const u8* __restrict__ gin,
                   const u8* __restrict__ Wsw, const float* __restrict__ bias,
                   const int* __restrict__ lens, u8* __restrict__ hout,
                   int b0, int hcol0, bool rev, long ginBase)
{
  constexpr int BUF = 16 * SA;
  const int tid = threadIdx.x;
  const int w = tid >> 6, L = tid & 63;
  const int lrow = L & 15, lq = L >> 4;
  const long* WswV = (const long*)Wsw;

  long wr[4][2][KC];
  #pragma unroll
  for (int gt = 0; gt < 4; ++gt)
    #pragma unroll
    for (int nt = 0; nt < 2; ++nt)
      #pragma unroll
      for (int kc = 0; kc < KC; ++kc)
        wr[gt][nt][kc] = WswV[(((w * 4 + gt) * 2 + nt) * KC + kc) * 64 + L];

  float bv[4][2];
  if constexpr (!GIN){
    #pragma unroll
    for (int gt = 0; gt < 4; ++gt)
      #pragma unroll
      for (int nt = 0; nt < 2; ++nt)
        bv[gt][nt] = bias[gt * 256 + w * 32 + nt * 16 + lrow];
  }

  unsigned lpack = 0;
  #pragma unroll
  for (int r = 0; r < 4; ++r)
    lpack |= (unsigned)lens[b0 + lq * 4 + r] << (8 * r);

  float cst[2][4];
  us16 hst[4];                              // packed fp8 pair state per r
  #pragma unroll
  for (int r = 0; r < 4; ++r){ hst[r] = 0; cst[0][r] = 0.0f; cst[1][r] = 0.0f; }

  for (int e = tid; e < 16 * 32; e += 512)   // zero h region of buf0
    *(long*)&abuf[(e >> 5) * SA + (e & 31) * 8] = 0;

  const int t0 = rev ? 199 : 0;
  if constexpr (!GIN){
    if (tid < (16 * XDIM) >> 3){
      int r = tid / (XDIM >> 3), c8 = (tid % (XDIM >> 3)) * 8;
      *(long*)&abuf[r * SA + 256 + c8] =
        *(const long*)&xbuf[((long)(b0 + r) * 200 + t0) * XDIM + c8];
    }
  }
  i32x4 gA{}, gB{};
  if constexpr (GIN){
    const u8* gp = gin + ((ginBase + t0) * 512 + tid) * 32;
    gA = *(const i32x4*)gp; gB = *(const i32x4*)(gp + 16);
  }
  __syncthreads();

  for (int tau = 0; tau < 200; ++tau){
    const int t = rev ? (199 - tau) : tau;
    u8* cur = abuf + (tau & 1) * BUF;
    u8* nxt = abuf + ((tau & 1) ^ 1) * BUF;

    f32x4 acc[4][2];
    if constexpr (GIN){
      int g4[8];
      *(i32x4*)&g4[0] = gA; *(i32x4*)&g4[4] = gB;
      #pragma unroll
      for (int gt = 0; gt < 4; ++gt)
        #pragma unroll
        for (int nt = 0; nt < 2; ++nt){
          int dw = g4[gt * 2 + nt];
          acc[gt][nt] = (f32x4){fp8tof<0>(dw), fp8tof<1>(dw), fp8tof<2>(dw), fp8tof<3>(dw)};
        }
      int tn = (tau < 199) ? (rev ? 198 - tau : tau + 1) : t;   // prefetch next step
      const u8* gp = gin + ((ginBase + tn) * 512 + tid) * 32;
      gA = *(const i32x4*)gp; gB = *(const i32x4*)(gp + 16);
    } else {
      #pragma unroll
      for (int gt = 0; gt < 4; ++gt)
        #pragma unroll
        for (int nt = 0; nt < 2; ++nt)
          acc[gt][nt] = (f32x4){bv[gt][nt], bv[gt][nt], bv[gt][nt], bv[gt][nt]};
    }

    #pragma unroll
    for (int kc = 0; kc < KC; ++kc){
      long af = *(const long*)&cur[lrow * SA + kc * 32 + lq * 8];
      #pragma unroll
      for (int gt = 0; gt < 4; ++gt)
        #pragma unroll
        for (int nt = 0; nt < 2; ++nt)
          acc[gt][nt] = mfma16f8(af, wr[gt][nt][kc], acc[gt][nt]);
    }

    // epilogue: packed fp8 pair per r -> LDS nxt (+ deferred global store)
    us16 houtv[4];
    #pragma unroll
    for (int r = 0; r < 4; ++r){
      const int bm = lq * 4 + r;
      const bool mk = t < (int)((lpack >> (8 * r)) & 255u);
      float hnv[2];
      #pragma unroll
      for (int nt = 0; nt < 2; ++nt){
        float gi = acc[0][nt][r], gf = acc[1][nt][r];
        float gg = acc[2][nt][r], go = acc[3][nt][r];
        float cn = fsig(gf) * cst[nt][r] + fsig(gi) * ftanh(gg);
        if (mk) cst[nt][r] = cn;
        hnv[nt] = fsig(go) * ftanh(cn);
      }
      int pk = __builtin_amdgcn_cvt_pk_fp8_f32(hnv[0], hnv[1], 0, false);
      us16 p16 = (us16)(pk & 0xFFFF);
      if (mk) hst[r] = p16;
      houtv[r] = mk ? p16 : (us16)0;
      *(us16*)&nxt[bm * SA + w * 32 + lrow * 2] = hst[r];
    }

    if constexpr (!GIN){
      if (tau < 199){
        int tn = rev ? (198 - tau) : (tau + 1);
        if (tid < (16 * XDIM) >> 3){
          int r = tid / (XDIM >> 3), c8 = (tid % (XDIM >> 3)) * 8;
          *(long*)&nxt[r * SA + 256 + c8] =
            *(const long*)&xbuf[((long)(b0 + r) * 200 + tn) * XDIM + c8];
        }
      }
    }
    __syncthreads();
    // deferred hout stores: retire under next step's compute
    #pragma unroll
    for (int r = 0; r < 4; ++r){
      const int bm = lq * 4 + r;
      long ga = ((long)(b0 + bm) * 200 + t) * 512 + hcol0 + w * 32 + lrow * 2;
      *(us16*)&hout[ga] = houtv[r];
    }
  }
}

__global__ __launch_bounds__(512, 2) void k_lstm(
    const u8* __restrict__ char_vec, const u8* __restrict__ gin,
    const u8* __restrict__ wsw_cf, const u8* __restrict__ wsw_cb,
    const u8* __restrict__ wsw_wf, const u8* __restrict__ wsw_wb,
    const float* __restrict__ b_cf, const float* __restrict__ b_cb,
    const int* __restrict__ len_char, const int* __restrict__ len_word,
    u8* __restrict__ h_char, u8* __restrict__ h_word)
{
  const int dir   = blockIdx.x >> 4;
  const int slice = blockIdx.x & 15;
  const int b0 = slice * 16;
  __shared__ __align__(16) u8 abuf[2 * 16 * 304];

  if (dir == 0)
    lstm_body<9, 32, 304, false>(abuf, char_vec, nullptr, wsw_cf, b_cf,
                                 len_char, h_char, b0, 0, false, 0);
  else if (dir == 1)
    lstm_body<9, 32, 304, false>(abuf, char_vec, nullptr, wsw_cb, b_cb,
                                 len_char, h_char, b0, 256, true, 0);
  else if (dir == 2)
    lstm_body<8, 0, 280, true>(abuf, nullptr, gin, wsw_wf, nullptr,
                               len_word, h_word, b0, 0, false, (long)slice * 200);
  else
    lstm_body<8, 0, 280, true>(abuf, nullptr, gin, wsw_wb, nullptr,
                               len_word, h_word, b0, 256, true, (long)(16 + slice) * 200);
}

// ---------- fp8 FF GEMM (G1/G2): out = softplus(A[M,512]fp8 @ Wsw^T + bias) ----------
__global__ __launch_bounds__(256) void k_gemm8(
    const u8* __restrict__ A, const u8* __restrict__ Wsw,
    const float* __restrict__ bias, int N,
    us16* __restrict__ outp, int ostride, int ocol0)
{
  const int tid = threadIdx.x;
  const int w = tid >> 6, L = tid & 63;
  const int lrow = L & 15, lq = L >> 4;
  const int m0base = blockIdx.x * 128;
  const int ntbase = blockIdx.y * 8;
  __shared__ u8 At[128 * 40];
  f32x4 acc[8][2] = {};
  const long* WswV = (const long*)Wsw;
  const int srow = tid >> 1, scol = (tid & 1) * 16;

  for (int kc = 0; kc < 16; ++kc){
    const long ab = (long)(m0base + srow) * 512 + kc * 32 + scol;
    long v0 = *(const long*)&A[ab];
    long v1 = *(const long*)&A[ab + 8];
    *(long*)&At[srow * 40 + scol] = v0;
    *(long*)&At[srow * 40 + scol + 8] = v1;
    __syncthreads();
    long af0 = *(const long*)&At[(w * 32 + lrow) * 40 + lq * 8];
    long af1 = *(const long*)&At[(w * 32 + 16 + lrow) * 40 + lq * 8];
    #pragma unroll
    for (int nt = 0; nt < 8; ++nt){
      long bf = WswV[((ntbase + nt) * 16 + kc) * 64 + L];
      acc[nt][0] = mfma16f8(af0, bf, acc[nt][0]);
      acc[nt][1] = mfma16f8(af1, bf, acc[nt][1]);
    }
    __syncthreads();
  }
  #pragma unroll
  for (int nt = 0; nt < 8; ++nt){
    const int col = (ntbase + nt) * 16 + lrow;
    if (col >= N) continue;
    const float bvv = bias[col];
    #pragma unroll
    for (int m0 = 0; m0 < 2; ++m0){
      #pragma unroll
      for (int r = 0; r < 4; ++r){
        float v = fsoftplus(acc[nt][m0][r] + bvv);
        const int row = m0base + w * 32 + m0 * 16 + lq * 4 + r;
        outp[(long)row * ostride + ocol0 + col] = f2bf(v);
      }
    }
  }
}

// ---------- bf16 FF GEMM (G3/G4/G5) ----------
__global__ __launch_bounds__(256) void k_gemm(
    const us16* __restrict__ A, int KC, const us16* __restrict__ Wsw,
    const float* __restrict__ bias, int N,
    void* __restrict__ outp, int ostride, int ocol0, int out_f32)
{
  const int tid = threadIdx.x;
  const int w = tid >> 6, L = tid & 63;
  const int lrow = L & 15, lq = L >> 4;
  const int m0base = blockIdx.x * 128;
  const int ntbase = blockIdx.y * 8;
  const int Kd = KC * 32;
  __shared__ us16 At[128 * 40];
  f32x4 acc[8][2] = {};
  const short8* WswV = (const short8*)Wsw;
  const int srow = tid >> 1, scol = (tid & 1) * 16;

  for (int kc = 0; kc < KC; ++kc){
    const long abase = (long)(m0base + srow) * Kd + kc * 32 + scol;
    short8 v0 = *(const short8*)&A[abase];
    short8 v1 = *(const short8*)&A[abase + 8];
    *(short8*)&At[srow * 40 + scol] = v0;
    *(short8*)&At[srow * 40 + scol + 8] = v1;
    __syncthreads();
    short8 af0 = *(const short8*)&At[(w * 32 + lrow) * 40 + lq * 8];
    short8 af1 = *(const short8*)&At[(w * 32 + 16 + lrow) * 40 + lq * 8];
    #pragma unroll
    for (int nt = 0; nt < 8; ++nt){
      short8 bf = WswV[((ntbase + nt) * KC + kc) * 64 + L];
      acc[nt][0] = mfma16(af0, bf, acc[nt][0]);
      acc[nt][1] = mfma16(af1, bf, acc[nt][1]);
    }
    __syncthreads();
  }
  #pragma unroll
  for (int nt = 0; nt < 8; ++nt){
    const int col = (ntbase + nt) * 16 + lrow;
    if (col >= N) continue;
    const float bvv = bias[col];
    #pragma unroll
    for (int m0 = 0; m0 < 2; ++m0){
      #pragma unroll
      for (int r = 0; r < 4; ++r){
        float v = fsoftplus(acc[nt][m0][r] + bvv);
        const int row = m0base + w * 32 + m0 * 16 + lq * 4 + r;
        if (out_f32) ((float*)outp)[(long)row * ostride + ocol0 + col] = v;
        else         ((us16*)outp)[(long)row * ostride + ocol0 + col] = f2bf(v);
      }
    }
  }
}

// ---------- CRF NLL: one wave per batch row, logits staged in LDS ----------
__global__ void k_crf(const float* __restrict__ logits, const int* __restrict__ tags,
                      const int* __restrict__ lens, const float* __restrict__ trans,
                      float* __restrict__ nll)
{
  const int b = blockIdx.x;
  const int lane = threadIdx.x;            // 64
  __shared__ float sl[2400];               // [t][12]
  __shared__ float alpha[12];
  __shared__ float tmp[12];
  for (int e = lane; e < 2400; e += 64) sl[e] = logits[(long)b * 2400 + e];
  float tcol[12];
  if (lane < 12){
    #pragma unroll
    for (int i = 0; i < 12; ++i) tcol[i] = trans[i * 12 + lane];
    alpha[lane] = 0.0f;
  }
  const int len = lens[b];
  __syncthreads();
  for (int t = 0; t < len; ++t){
    float an = 0.0f;
    if (lane < 12){
      float mx = -3.0e38f;
      #pragma unroll
      for (int i = 0; i < 12; ++i) mx = fmaxf(mx, alpha[i] + tcol[i]);
      float ss = 0.0f;
      #pragma unroll
      for (int i = 0; i < 12; ++i)
        ss += __builtin_amdgcn_exp2f(1.4426950408889634f * (alpha[i] + tcol[i] - mx));
      an = sl[t * 12 + lane] + mx + 0.69314718055994531f * __builtin_amdgcn_logf(ss);
    }
    __syncthreads();
    if (lane < 12) alpha[lane] = an;
    __syncthreads();
  }
  if (lane < 12) tmp[lane] = alpha[lane] + trans[lane * 12 + 11];   // + trans[:,STOP]
  __syncthreads();
  float rs = 0.0f;
  for (int t = lane; t < len; t += 64){
    int tg = tags[b * 200 + t];
    int pv = (t == 0) ? 10 : tags[b * 200 + t - 1];                 // START=10
    rs += sl[t * 12 + tg] + trans[pv * 12 + tg];
  }
  #pragma unroll
  for (int off = 32; off > 0; off >>= 1) rs += __shfl_down(rs, off, 64);
  if (lane == 0){
    float mx = -3.0e38f;
    for (int i = 0; i < 12; ++i) mx = fmaxf(mx, tmp[i]);
    float ss = 0.0f;
    for (int i = 0; i < 12; ++i)
      ss += __builtin_amdgcn_exp2f(1.4426950408889634f * (tmp[i] - mx));
    float total = mx + 0.69314718055994531f * __builtin_amdgcn_logf(ss);
    rs += trans[tags[b * 200 + len - 1] * 12 + 11];                 // trans[last, STOP]
    nll[b] = total - rs;
  }
}

__global__ void k_sum(const float* __restrict__ nll, float* __restrict__ out){
  __shared__ float red[256];
  int t = threadIdx.x;
  red[t] = nll[t];
  __syncthreads();
  for (int s = 128; s > 0; s >>= 1){
    if (t < s) red[t] += red[t + s];
    __syncthreads();
  }
  if (t == 0) out[0] = red[0];
}

// ---------- launcher ----------
extern "C" void kernel_launch(void* const* d_in, const int* in_sizes, int n_in,
                              void* d_out, int out_size, void* d_ws, size_t ws_size,
                              hipStream_t stream)
{
  (void)in_sizes; (void)n_in; (void)out_size; (void)ws_size;
  const int*   characters = (const int*)  d_in[0];
  const float* words      = (const float*)d_in[1];
  const int*   tags       = (const int*)  d_in[2];
  const int*   len_char   = (const int*)  d_in[3];
  const int*   len_word   = (const int*)  d_in[4];
  const float* char_emb   = (const float*)d_in[5];
  const float* char_Wih_f = (const float*)d_in[6];
  const float* char_Whh_f = (const float*)d_in[7];
  const float* char_b_f   = (const float*)d_in[8];
  const float* char_Wih_b = (const float*)d_in[9];
  const float* char_Whh_b = (const float*)d_in[10];
  const float* char_b_b   = (const float*)d_in[11];
  const float* char_lin_W = (const float*)d_in[12];
  const float* char_lin_b = (const float*)d_in[13];
  const float* word_Wih_f = (const float*)d_in[14];
  const float* word_Whh_f = (const float*)d_in[15];
  const float* word_b_f   = (const float*)d_in[16];
  const float* word_Wih_b = (const float*)d_in[17];
  const float* word_Whh_b = (const float*)d_in[18];
  const float* word_b_b   = (const float*)d_in[19];
  const float* word_lin_W = (const float*)d_in[20];
  const float* word_lin_b = (const float*)d_in[21];
  const float* lin1_W     = (const float*)d_in[22];
  const float* lin1_b     = (const float*)d_in[23];
  const float* lin2_W     = (const float*)d_in[24];
  const float* lin2_b     = (const float*)d_in[25];
  const float* tag_W      = (const float*)d_in[26];
  const float* tag_b      = (const float*)d_in[27];
  const float* trans      = (const float*)d_in[28];

  char* ws = (char*)d_ws;
  size_t off = 0;
  auto take = [&](size_t bytes) -> char* {
    char* p = ws + off;
    off = (off + bytes + 511) & ~(size_t)511;
    return p;
  };
  u8*   char_vec = (u8*)take((size_t)256*200*32);          //  1.6 MB fp8
  u8*   words_f8 = (u8*)take((size_t)256*200*128);         //  6.3 MB fp8
  u8*   wsw_cf   = (u8*)take((size_t)64*9*512);
  u8*   wsw_cb   = (u8*)take((size_t)64*9*512);
  u8*   wsw_wf   = (u8*)take((size_t)64*8*512);
  u8*   wsw_wb   = (u8*)take((size_t)64*8*512);
  u8*   wswgin_f = (u8*)take((size_t)64*4*512);
  u8*   wswgin_b = (u8*)take((size_t)64*4*512);
  u8*   wswg1    = (u8*)take((size_t)32*16*512);           // fp8, pi-permuted k
  u8*   wswg2    = (u8*)take((size_t)16*16*512);           // fp8, pi-permuted k
  us16* wswg3    = (us16*)take((size_t)32*23*512*2);
  us16* wswg4    = (us16*)take((size_t)16*16*512*2);
  us16* wswg5    = (us16*)take((size_t)8*8*512*2);
  float* logits  = (float*)take((size_t)51200*12*4);
  float* nll     = (float*)take((size_t)256*4);
  u8*   h_char   = (u8*)take((size_t)51200*512);           // 25 MB fp8 (pi-permuted)
  u8*   h_word   = (u8*)take((size_t)51200*512);           // 25 MB fp8
  us16* x1       = (us16*)take((size_t)51200*512*2);       // 50 MB bf16
  u8*   gin      = (u8*)take((size_t)2*3200*512*32);       // 100 MB; dead after k_lstm
  us16* x_cat    = (us16*)gin;            // 72 MB, written after k_lstm
  us16* x2       = (us16*)gin;            // 25 MB, written after G3 (x_cat dead)

  // preprocessing
  k_embed<<<6400, 256, 0, stream>>>(characters, char_emb, char_vec);
  k_cvt8<<<(256*200*128 + 255)/256, 256, 0, stream>>>(words, words_f8, 256*200*128);
  k_swz_lstm<<<(64*9*512 + 255)/256, 256, 0, stream>>>(char_Whh_f, char_Wih_f, 30, 9, wsw_cf);
  k_swz_lstm<<<(64*9*512 + 255)/256, 256, 0, stream>>>(char_Whh_b, char_Wih_b, 30, 9, wsw_cb);
  k_swz_lstm<<<(64*8*512 + 255)/256, 256, 0, stream>>>(word_Whh_f, word_Wih_f, 0, 8, wsw_wf);
  k_swz_lstm<<<(64*8*512 + 255)/256, 256, 0, stream>>>(word_Whh_b, word_Wih_b, 0, 8, wsw_wb);
  k_swz_gin<<<(64*4*512 + 255)/256, 256, 0, stream>>>(word_Wih_f, wswgin_f);
  k_swz_gin<<<(64*4*512 + 255)/256, 256, 0, stream>>>(word_Wih_b, wswgin_b);
  k_swz_ff8<<<(32*16*512 + 255)/256, 256, 0, stream>>>(char_lin_W, 512, wswg1, 32*16*512);
  k_swz_ff8<<<(16*16*512 + 255)/256, 256, 0, stream>>>(word_lin_W, 200, wswg2, 16*16*512);
  k_swz_ff<<<(32*23*512 + 255)/256, 256, 0, stream>>>(lin1_W, 512, 712, 23, wswg3, 32*23*512);
  k_swz_ff<<<(16*16*512 + 255)/256, 256, 0, stream>>>(lin2_W, 256, 512, 16, wswg4, 16*16*512);
  k_swz_ff<<<(8*8*512 + 255)/256, 256, 0, stream>>>(tag_W, 12, 256, 8, wswg5, 8*8*512);

  // gin precompute (word Wih.x + b, fp8, 4 timesteps/block)
  k_gin<<<1600, 512, 0, stream>>>(words_f8, wswgin_f, wswgin_b, word_b_f, word_b_b, gin);

  // recurrences: 64 blocks, register-resident weights, packed-fp8 h
  k_lstm<<<64, 512, 0, stream>>>(char_vec, gin, wsw_cf, wsw_cb, wsw_wf, wsw_wb,
                                 char_b_f, char_b_b, len_char, len_word, h_char, h_word);

  // x_cat padding (x_cat aliases gin -> after k_lstm)
  k_zpad<<<4800, 256, 0, stream>>>(x_cat);

  // feed-forward chain
  k_gemm8<<<dim3(400, 4), 256, 0, stream>>>(h_char, wswg1, char_lin_b, 512, x_cat, 736,   0);
  k_gemm8<<<dim3(400, 2), 256, 0, stream>>>(h_word, wswg2, word_lin_b, 200, x_cat, 736, 512);
  k_gemm<<<dim3(400, 4), 256, 0, stream>>>(x_cat, 23, wswg3, lin1_b, 512, x1, 512, 0, 0);
  k_gemm<<<dim3(400, 2), 256, 0, stream>>>(x1,    16, wswg4, lin2_b, 256, x2, 256, 0, 0);
  k_gemm<<<dim3(400, 1), 256, 0, stream>>>(x2,     8, wswg5, tag_b,   12, logits, 12, 0, 1);

  // CRF
  k_crf<<<256, 64, 0, stream>>>(logits, tags, len_char, trans, nll);
  k_sum<<<1, 256, 0, stream>>>(nll, (float*)d_out);
}